// Round 10
// baseline (121.314 us; speedup 1.0000x reference)
//
#include <hip/hip_runtime.h>
#include <hip/hip_bf16.h>
#include <math.h>

#define NQ 900
#define NT 100
#define BS 16
#define NH 7
#define NC 16
#define NSLOT 16      // 4 chunks (kc) x 4 elems (e); column idx = 4*lane + 256*kc + e
#define MAXTREE 8192  // per-phase tree guard (no hang on bug)

// ---------- Stage 1a: sigmoid + transpose probs: [h,b,q,c] -> [h,b,c,q] ----------
__global__ __launch_bounds__(256) void sig_transpose_kernel(const float* __restrict__ logits,
                                                            float* __restrict__ probsT) {
    const int hb = blockIdx.x;                       // 0..NH*BS-1
    const float* src = logits + (size_t)hb * NQ * NC;
    float* dst = probsT + (size_t)hb * NC * NQ;
    __shared__ float tile[NC][NQ + 1];
    for (int e = threadIdx.x; e < NQ * NC; e += 256) {
        int q = e >> 4, c = e & 15;
        float x = src[e];
        tile[c][q] = 1.0f / (1.0f + expf(-x));       // same formula as R0 -> identical costT
    }
    __syncthreads();
    for (int c = 0; c < NC; ++c)
        for (int q = threadIdx.x; q < NQ; q += 256)
            dst[c * NQ + q] = tile[c][q];
}

// ---------- Stage 1b: cost matrix (transposed [b][t][q]); one block per (b,t) ----------
__global__ __launch_bounds__(256) void cost_kernel_bt(const float4* __restrict__ pboxes4,
                                                      const float4* __restrict__ tboxes4,
                                                      const int*    __restrict__ tlabels,
                                                      const float*  __restrict__ probsT,
                                                      float* __restrict__ costT) {
    const int bt = blockIdx.x;
    const int b = bt / NT, t = bt % NT;

    const float* prow[NH];
    #pragma unroll
    for (int h = 0; h < NH; ++h) {
        int lab = tlabels[(h * BS + b) * NT + t];          // uniform -> scalar load
        prow[h] = probsT + (size_t)((h * BS + b) * NC + lab) * NQ;
    }

    float4 tb = tboxes4[b * NT + t];
    float tx = tb.x, ty = tb.y, tw = tb.z, th = tb.w;
    float bx0 = tx - 0.5f * tw, by0 = ty - 0.5f * th;
    float bx1 = tx + 0.5f * tw, by1 = ty + 0.5f * th;
    float areaB = (bx1 - bx0) * (by1 - by0);

    for (int q = threadIdx.x; q < NQ; q += 256) {
        float4 pb = pboxes4[b * NQ + q];
        float px = pb.x, py = pb.y, pw = pb.z, ph = pb.w;

        float cost_bbox = fabsf(px - tx) + fabsf(py - ty) + fabsf(pw - tw) + fabsf(ph - th);

        float ax0 = px - 0.5f * pw, ay0 = py - 0.5f * ph;
        float ax1 = px + 0.5f * pw, ay1 = py + 0.5f * ph;
        float areaA = (ax1 - ax0) * (ay1 - ay0);
        float ltx = fmaxf(ax0, bx0), lty = fmaxf(ay0, by0);
        float rbx = fminf(ax1, bx1), rby = fminf(ay1, by1);
        float iw = fmaxf(rbx - ltx, 0.f), ih = fmaxf(rby - lty, 0.f);
        float inter = iw * ih;
        float uni = areaA + areaB - inter;
        float iou = inter / uni;
        float ex0 = fminf(ax0, bx0), ey0 = fminf(ay0, by0);
        float ex1 = fmaxf(ax1, bx1), ey1 = fmaxf(ay1, by1);
        float ew = fmaxf(ex1 - ex0, 0.f), eh = fmaxf(ey1 - ey0, 0.f);
        float earea = ew * eh;
        float giou = iou - (earea - uni) / earea;

        float ssum = 0.f;
        #pragma unroll
        for (int h = 0; h < NH; ++h) ssum += prow[h][q];   // coalesced in q

        costT[(b * NT + t) * NQ + q] = 5.0f * cost_bbox - 2.0f * ssum - 2.0f * giou;
    }
}

// ---------- Fallback stage 1 (ws too small): direct strided gather ----------
__global__ void cost_kernel_fb(const float* __restrict__ logits,
                               const float* __restrict__ pboxes,
                               const float* __restrict__ tboxes,
                               const int*   __restrict__ tlabels,
                               float* __restrict__ costT) {
    int id = blockIdx.x * blockDim.x + threadIdx.x;
    if (id >= BS * NT * NQ) return;
    int q = id % NQ;
    int t = (id / NQ) % NT;
    int b = id / (NQ * NT);

    const float* pb = pboxes + (b * NQ + q) * 4;
    const float* tb = tboxes + (b * NT + t) * 4;
    float px = pb[0], py = pb[1], pw = pb[2], ph = pb[3];
    float tx = tb[0], ty = tb[1], tw = tb[2], th = tb[3];

    float cost_bbox = fabsf(px - tx) + fabsf(py - ty) + fabsf(pw - tw) + fabsf(ph - th);

    float ax0 = px - 0.5f * pw, ay0 = py - 0.5f * ph;
    float ax1 = px + 0.5f * pw, ay1 = py + 0.5f * ph;
    float bx0 = tx - 0.5f * tw, by0 = ty - 0.5f * th;
    float bx1 = tx + 0.5f * tw, by1 = ty + 0.5f * th;
    float areaA = (ax1 - ax0) * (ay1 - ay0);
    float areaB = (bx1 - bx0) * (by1 - by0);
    float ltx = fmaxf(ax0, bx0), lty = fmaxf(ay0, by0);
    float rbx = fminf(ax1, bx1), rby = fminf(ay1, by1);
    float iw = fmaxf(rbx - ltx, 0.f), ih = fmaxf(rby - lty, 0.f);
    float inter = iw * ih;
    float uni = areaA + areaB - inter;
    float iou = inter / uni;
    float ex0 = fminf(ax0, bx0), ey0 = fminf(ay0, by0);
    float ex1 = fmaxf(ax1, bx1), ey1 = fmaxf(ay1, by1);
    float ew = fmaxf(ex1 - ex0, 0.f), eh = fmaxf(ey1 - ey0, 0.f);
    float earea = ew * eh;
    float giou = iou - (earea - uni) / earea;

    float ssum = 0.f;
    #pragma unroll
    for (int h = 0; h < NH; ++h) {
        int lab = tlabels[(h * BS + b) * NT + t];
        float x = logits[((h * BS + b) * NQ + q) * NC + lab];
        ssum += 1.0f / (1.0f + expf(-x));
    }

    costT[(b * NT + t) * NQ + q] = 5.0f * cost_bbox - 2.0f * ssum - 2.0f * giou;
}

// ---------- Stage 2: JV LSA, v=0 init (rectangular-correct), exact SAP tree ----------
// R8-passing decision structure, unchanged. R9 changes (scheduling only):
//  * way2[slot][lane] layout -> conflict-free LDS writes in the scan
//  * loop rotated: next cost row loads issue right after pu[jwin] read; stage-D
//    dual updates + stage-A marks execute under the L2 fetch latency.
__global__ __launch_bounds__(64) void lsa_kernel(const float* __restrict__ costT,
                                                 int* __restrict__ out) {
    const int b = blockIdx.x;
    const int lane = threadIdx.x;
    const float* cost = costT + b * NT * NQ;   // [t][q]

    __shared__ double2 pu[NQ + 1];     // {u[p[j]], p[j]} (p=0 -> free)
    __shared__ double u_s[NT + 1];
    __shared__ int way2[NSLOT][64];    // way, owner-lane layout (conflict-free)
    __shared__ int p_w[NQ + 1];        // greedy atomicMin arena
    __shared__ int jmin_s[NT];
    __shared__ int listA[NT];
    __shared__ int r2c[NT];
    __shared__ int cnt_s;

    for (int j = lane; j <= NQ; j += 64) {
        pu[j] = make_double2(0.0, 0.0);
        p_w[j] = 0x7fffffff;
    }
    __syncthreads();

    // ---- row minima + argmin (v = 0); greedy claim via atomicMin ----
    bool lostA = false, lostB = false;
    #pragma unroll
    for (int pass = 0; pass < 2; ++pass) {
        int r = pass * 64 + lane;
        if (r < NT) {
            const float4* row4 = (const float4*)(cost + (size_t)r * NQ);
            float m0 = INFINITY, m1f = INFINITY, m2f = INFINITY, m3f = INFINITY;
            int i0 = 0, i1 = 0, i2 = 0, i3 = 0;
            #pragma unroll 5
            for (int q4 = 0; q4 < NQ / 4; ++q4) {
                float4 cv = row4[q4];
                if (cv.x < m0)  { m0 = cv.x;  i0 = 4 * q4; }
                if (cv.y < m1f) { m1f = cv.y; i1 = 4 * q4 + 1; }
                if (cv.z < m2f) { m2f = cv.z; i2 = 4 * q4 + 2; }
                if (cv.w < m3f) { m3f = cv.w; i3 = 4 * q4 + 3; }
            }
            float mv = m0; int mj = i0;
            if (m1f < mv || (m1f == mv && i1 < mj)) { mv = m1f; mj = i1; }
            if (m2f < mv || (m2f == mv && i2 < mj)) { mv = m2f; mj = i2; }
            if (m3f < mv || (m3f == mv && i3 < mj)) { mv = m3f; mj = i3; }
            u_s[r + 1] = (double)mv;    // u = rowmin (exact); v stays 0
            jmin_s[r] = mj;
            atomicMin(&p_w[mj + 1], r + 1);
        }
    }
    __syncthreads();

    // resolve winners (deterministic: smallest row wins each contested column)
    {
        int rA = lane;
        int j = jmin_s[rA] + 1;
        if (p_w[j] == rA + 1) pu[j] = make_double2(u_s[rA + 1], (double)(rA + 1));
        else lostA = true;
    }
    if (lane < NT - 64) {
        int rB = 64 + lane;
        int j = jmin_s[rB] + 1;
        if (p_w[j] == rB + 1) pu[j] = make_double2(u_s[rB + 1], (double)(rB + 1));
        else lostB = true;
    }
    // deterministic ascending free-row list via ballot bit-scan
    unsigned long long mA = __ballot(lostA);
    unsigned long long mB = __ballot(lostB);
    if (lane == 0) {
        int n = 0;
        unsigned long long m = mA;
        while (m) { int l = __ffsll((unsigned long long)m) - 1; listA[n++] = l + 1; m &= m - 1; }
        m = mB;
        while (m) { int l = __ffsll((unsigned long long)m) - 1; listA[n++] = 64 + l + 1; m &= m - 1; }
        cnt_s = n;
    }
    __syncthreads();
    const int nfree = cnt_s;

    // lane-owned columns: slot s = 4*kc + e -> idx = 4*lane + 256*kc + e, j = idx+1
    double v[NSLOT], minv[NSLOT], ureg[NSLOT];
    int pof[NSLOT];
    #pragma unroll
    for (int k = 0; k < NSLOT; ++k) { v[k] = 0.0; ureg[k] = 0.0; pof[k] = 0; }
    // kc=3 covers idx 768..899 -> valid lanes 0..32 only
    const unsigned invalid = (lane <= 32) ? 0u : 0xF000u;
    double u_c0 = 0.0;

    // ---- exact SAP tree stage ----
    for (int ii = 0; ii < nfree; ++ii) {
        const int i = listA[ii];
        #pragma unroll
        for (int k = 0; k < NSLOT; ++k) minv[k] = INFINITY;
        unsigned used = invalid;
        int j0 = 0;
        int i0 = i;
        double u_i0 = u_s[i];

        // initial row fetch
        const float4* crow4 = (const float4*)(cost + (size_t)(i0 - 1) * NQ);
        float4 c4[4];
        #pragma unroll
        for (int kc = 0; kc < 3; ++kc) c4[kc] = crow4[lane + 64 * kc];
        c4[3] = (lane <= 32) ? crow4[lane + 192] : make_float4(0.f, 0.f, 0.f, 0.f);

        int guard = 0;
        while (guard++ < MAXTREE) {
            // stage A: mark j0 used (owner lane records row + running u)
            if (j0 != 0) {
                int idx = j0 - 1;
                if (lane == ((idx >> 2) & 63)) {
                    int slot = ((idx >> 8) << 2) | (idx & 3);
                    used |= (1u << slot);
                    #pragma unroll
                    for (int s = 0; s < NSLOT; ++s)
                        if (s == slot) { pof[s] = i0; ureg[s] = u_i0; }
                }
            } else {
                if (lane == 0) u_c0 = u_i0;
            }

            // stage B: scan free columns (cur = (c - u) - v); lane-local argmin asc-j
            double bv = INFINITY;
            int bj = 2048;
            #pragma unroll
            for (int kc = 0; kc < 4; ++kc) {
                #pragma unroll
                for (int e = 0; e < 4; ++e) {
                    const int s = 4 * kc + e;
                    if (!((used >> s) & 1u)) {
                        float cf = (e == 0) ? c4[kc].x : (e == 1) ? c4[kc].y
                                 : (e == 2) ? c4[kc].z : c4[kc].w;
                        int j = 1 + 4 * lane + 256 * kc + e;
                        double cur = ((double)cf - u_i0) - v[s];
                        if (cur < minv[s]) { minv[s] = cur; way2[s][lane] = j0; }
                        if (minv[s] < bv) { bv = minv[s]; bj = j; }
                    }
                }
            }
            // value-only EXACT f64 min butterfly
            double vmin = bv;
            #pragma unroll
            for (int off = 1; off < 64; off <<= 1)
                vmin = fmin(vmin, __shfl_xor(vmin, off));
            // winner = first lane achieving the exact min; its bj (lane-local asc-j)
            unsigned long long tied = __ballot(bv == vmin);
            int wl = __ffsll((unsigned long long)tied) - 1;
            int jwin = __shfl(bj, wl);
            const double delta = vmin;

            // advance-read; then ISSUE next row loads immediately (prefetch),
            // so stage D's VALU work covers the L2 latency
            double2 t = pu[jwin];
            const int i0n = (int)t.y;
            float4 c4n[4];
            if (i0n != 0) {
                const float4* nrow4 = (const float4*)(cost + (size_t)(i0n - 1) * NQ);
                #pragma unroll
                for (int kc = 0; kc < 3; ++kc) c4n[kc] = nrow4[lane + 64 * kc];
                c4n[3] = (lane <= 32) ? nrow4[lane + 192] : make_float4(0.f, 0.f, 0.f, 0.f);
            }

            // stage D: dual update (register-resident; independent of the loads)
            #pragma unroll
            for (int s = 0; s < NSLOT; ++s) {
                minv[s] -= delta;              // harmless for used slots (never read)
                if ((used >> s) & 1u) { ureg[s] += delta; v[s] -= delta; }
            }
            if (lane == 0) u_c0 += delta;

            j0 = jwin;
            if (i0n == 0) break;
            i0 = i0n;
            u_i0 = t.x;
            #pragma unroll
            for (int kc = 0; kc < 4; ++kc) c4[kc] = c4n[kc];
        }

        __syncthreads();
        // owner writebacks: u of rows sitting on used columns
        #pragma unroll
        for (int s = 0; s < NSLOT; ++s) {
            if (((used >> s) & 1u) && !((invalid >> s) & 1u)) {
                int j = 1 + 4 * lane + 256 * (s >> 2) + (s & 3);
                u_s[pof[s]] = ureg[s];
                pu[j] = make_double2(ureg[s], (double)pof[s]);
            }
        }
        __syncthreads();
        if (lane == 0) {
            u_s[i] = u_c0;
            int j = j0;
            while (j) {
                int idx = j - 1;
                int ol = (idx >> 2) & 63;
                int sl = ((idx >> 8) << 2) | (idx & 3);
                int jw = way2[sl][ol];
                double2 t2 = (jw == 0) ? make_double2(u_c0, (double)i) : pu[jw];
                pu[j] = t2;
                j = jw;
            }
        }
        __syncthreads();
    }

    // ---- row2col + stable-argsort ranks ----
    for (int j = 1 + lane; j <= NQ; j += 64) {
        int pi = (int)pu[j].y;
        if (pi > 0) r2c[pi - 1] = j - 1;
    }
    __syncthreads();
    for (int t = lane; t < NT; t += 64) {
        int ccol = r2c[t];
        int rank = 0;
        for (int tt = 0; tt < NT; ++tt) rank += (r2c[tt] < ccol) ? 1 : 0;
        out[b * 2 * NT + rank] = ccol;         // out[b,0,rank] = pred idx
        out[b * 2 * NT + NT + rank] = t;       // out[b,1,rank] = target idx
    }
}

extern "C" void kernel_launch(void* const* d_in, const int* in_sizes, int n_in,
                              void* d_out, int out_size, void* d_ws, size_t ws_size,
                              hipStream_t stream) {
    const float* logits  = (const float*)d_in[0];  // (7,16,900,16)
    const float* pboxes  = (const float*)d_in[1];  // (16,900,4)
    const float* tboxes  = (const float*)d_in[2];  // (16,100,4)
    const int*   tlabels = (const int*)d_in[3];    // (7,16,100)
    int* out = (int*)d_out;                        // (16,2,100) int32
    float* costT = (float*)d_ws;                   // 1,440,000 floats = 5.76 MB

    const size_t costT_elems  = (size_t)BS * NT * NQ;
    const size_t probsT_elems = (size_t)NH * BS * NC * NQ;
    const size_t need = (costT_elems + probsT_elems) * sizeof(float);

    if (ws_size >= need) {
        float* probsT = costT + costT_elems;
        sig_transpose_kernel<<<NH * BS, 256, 0, stream>>>(logits, probsT);
        cost_kernel_bt<<<BS * NT, 256, 0, stream>>>((const float4*)pboxes,
                                                    (const float4*)tboxes, tlabels, probsT, costT);
    } else {
        const int total = BS * NT * NQ;
        cost_kernel_fb<<<(total + 255) / 256, 256, 0, stream>>>(logits, pboxes, tboxes, tlabels, costT);
    }
    lsa_kernel<<<BS, 64, 0, stream>>>(costT, out);
}